// Round 10
// baseline (244.840 us; speedup 1.0000x reference)
//
#include <hip/hip_runtime.h>
#include <hip/hip_bf16.h>
#include <math.h>
#include <cstddef>

#define HDIM 64
#define WDIM 2048
#define HW   (HDIM*WDIM)      // 131072
#define BATCH 2
#define CIN  64
#define COUT 64
#define XC   (3+CIN)          // 67
#define NPIX (BATCH*HW)       // 262144
#define NBLK (NPIX/64)        // 4096 blocks, 64 pixels each
#define NB2  (NBLK*2)         // 2 partial slots per block (px halves)
#define EPS  1e-5f

typedef short  short8  __attribute__((ext_vector_type(8)));
typedef float  f32x16  __attribute__((ext_vector_type(16)));
typedef float  f32x2   __attribute__((ext_vector_type(2)));   // -> v_pk_* (VOP3P)

__device__ __forceinline__ unsigned short f2bf(float f) {
    unsigned int u = __float_as_uint(f);
    u += 0x7fff + ((u >> 16) & 1);        // round-to-nearest-even
    return (unsigned short)(u >> 16);
}

// LDS 13,568 B.
// V rows padded 64->72 ushorts: b128 frag reads start bank 4*mrow%32 ->
// 8 start groups = conflict-free (measured 0 conflicts rounds 0/4/7/9).
// exp(wc-M) values live in REGISTERS (ev[16]) -- the staging thread (q,px)
// is the same thread that computed them.
struct __align__(16) SmemA {
    float wsm[9][64];            // softmax(ws)[k] * mask[k], [k][px]
    float wcpart[4][64];         // per-wave max of wc logits
    float wcsum[4][64];          // per-wave sum exp(logit - M)
    union {
        unsigned short V[64][72];    // weighted feat [px][c] bf16 (per tap)
        float wspart[9][4][64];      // phase-1 ws partial max (dead before V)
    } u;
};

// one-time: w_agg fp32 -> bf16, PRE-SWIZZLED into MFMA fragment order:
// wbf[((kk*4+ks)*2+half)*64 + co][8] = w_agg[co][kk*64+ks*16+half*8 .. +8]
__global__ __launch_bounds__(256)
void kernelW(const float* __restrict__ w_agg, unsigned short* __restrict__ wbf)
{
    int t = blockIdx.x*256 + threadIdx.x;    // 4608 threads total
    int co  = t / 72;
    int rem = t % 72;
    int kk  = rem >> 3;
    int ks  = (rem >> 1) & 3;
    int half= rem & 1;
    const float* src = w_agg + (size_t)co*576 + kk*64 + ks*16 + half*8;
    unsigned long long pk0 = 0, pk1 = 0;
    #pragma unroll
    for (int j=0;j<4;++j) pk0 |= (unsigned long long)f2bf(src[j])   << (16*j);
    #pragma unroll
    for (int j=0;j<4;++j) pk1 |= (unsigned long long)f2bf(src[4+j]) << (16*j);
    unsigned long long* dst =
        (unsigned long long*)(wbf + ((size_t)(((kk*4+ks)*2+half)*64 + co))*8);
    dst[0] = pk0; dst[1] = pk1;
}

// NOTE: min-waves clamp MUST stay at 4. Round 3 used (256,6) -> VGPR forced
// to 40 -> acc/p/wclog spilled to scratch -> FETCH 71->770 MB, 2.9x slower.
// NOTE: stats epilogue MUST stay psum/psq stores (distinct addresses).
// Round 6 used atomicAdd into 128 floats -> 1M same-address atomics ->
// kernelA 136 -> 1597 us (atomic serialization, all pipes idle).
// NOTE: R8's channel-pair pk attempt spilled because float4 VGPR weight
// loads + doubled f32x2 state hit the 64-VGPR cliff. This round packs
// TAP pairs instead: the broadcast operand is the wave-uniform weight
// (SGPR, free broadcast in VOP3P), per-lane state stays ~same size.
__global__ __launch_bounds__(256, 4)
void kernelA(const float* __restrict__ x, const int* __restrict__ mask,
             const float* __restrict__ w_sp, const float* __restrict__ b_sp,
             const float* __restrict__ w_ch, const float* __restrict__ b_ch,
             const unsigned short* __restrict__ wbf,
             float* __restrict__ out, float* __restrict__ psum, float* __restrict__ psq)
{
    __shared__ SmemA s;
    const int tid = threadIdx.x;
    // XCD-aware swizzle (T1): 4096 blocks % 8 XCDs == 0 -> bijective.
    // Measured R9: FETCH 74.5 -> 38.6 MB, kernelA -37 us. KEEP.
    const int bid = ((blockIdx.x & 7) << 9) | (blockIdx.x >> 3);
    const int b  = bid >> 11;
    const int r  = bid & 2047;
    const int h  = r >> 5;
    const int w0 = (r & 31) << 6;

    const int px = tid & 63;
    const int q  = tid >> 6;

    // ---------------- phase 1: per-pixel attention logits ----------------
    float p[9][4];
    float mkr[9];
    {
        const int wpix = w0 + px;
        #pragma unroll
        for (int k = 0; k < 9; ++k) {
            int hh = h + k/3 - 1;
            int ww = wpix + k%3 - 1;
            bool in = (hh >= 0) && (hh < HDIM) && (ww >= 0) && (ww < WDIM);
            float p0=0.f, p1=0.f, p2=0.f, mv=0.f;
            if (in) {
                size_t base = ((size_t)(b*XC)*HDIM + hh)*(size_t)WDIM + ww;
                p0 = x[base];
                p1 = x[base + (size_t)HW];
                p2 = x[base + 2*(size_t)HW];
                mv = (float)mask[((size_t)b*HDIM + hh)*(size_t)WDIM + ww];
            }
            p[k][0]=p0; p[k][1]=p1; p[k][2]=p2;
            p[k][3]=sqrtf(p0*p0 + p1*p1 + p2*p2);
            mkr[k]=mv;
        }
        float c0=p[4][0], c1=p[4][1], c2=p[4][2], c3=p[4][3];
        #pragma unroll
        for (int k = 0; k < 9; ++k) {
            p[k][0]-=c0; p[k][1]-=c1; p[k][2]-=c2; p[k][3]-=c3;
        }
    }

    // pack the 8 non-center taps into 4 tap-pairs (tap 4 is zero after
    // centering -> handled as sv=bs / tv=bc directly).
    f32x2 pp[4][4];                  // [tap-pair][feature m]
    {
        const int kpA[4] = {0, 2, 5, 7};
        #pragma unroll
        for (int kp=0; kp<4; ++kp) {
            int ka = kpA[kp];
            #pragma unroll
            for (int m=0; m<4; ++m) pp[kp][m] = f32x2{p[ka][m], p[ka+1][m]};
        }
    }

    // channel loop over 16 wave-uniform channels; per channel:
    // 32 v_pk_fma + 8 v_pk_max instead of 64 scalar fma + 16 scalar max.
    f32x2 ws2[4];                    // per tap-pair running max over channels
    #pragma unroll
    for (int kp=0;kp<4;++kp) ws2[kp] = f32x2{-1e30f,-1e30f};
    float wsp4 = -1e30f;
    float wclog[16];                 // wc logit (max over taps), in registers
    float cqm = -1e30f;              // wave-partial max over 16 channels
    for (int cc = 0; cc < 16; ++cc) {
        int c = q*16 + cc;                       // wave-uniform -> scalar loads
        float a0=w_sp[c*4+0], a1=w_sp[c*4+1], a2=w_sp[c*4+2], a3=w_sp[c*4+3], bs=b_sp[c];
        float d0=w_ch[c*4+0], d1=w_ch[c*4+1], d2=w_ch[c*4+2], d3=w_ch[c*4+3], bc=b_ch[c];
        const f32x2 A0{a0,a0}, A1{a1,a1}, A2{a2,a2}, A3{a3,a3}, BS{bs,bs};
        const f32x2 D0{d0,d0}, D1{d1,d1}, D2{d2,d2}, D3{d3,d3}, BC{bc,bc};
        wsp4 = fmaxf(wsp4, bs);
        f32x2 tm2 = BC;                          // tap-4 tv == bc
        #pragma unroll
        for (int kp=0; kp<4; ++kp) {
            f32x2 sv = BS;
            sv = __builtin_elementwise_fma(pp[kp][0], A0, sv);
            sv = __builtin_elementwise_fma(pp[kp][1], A1, sv);
            sv = __builtin_elementwise_fma(pp[kp][2], A2, sv);
            sv = __builtin_elementwise_fma(pp[kp][3], A3, sv);
            ws2[kp] = __builtin_elementwise_max(ws2[kp], sv);
            f32x2 tv = BC;
            tv = __builtin_elementwise_fma(pp[kp][0], D0, tv);
            tv = __builtin_elementwise_fma(pp[kp][1], D1, tv);
            tv = __builtin_elementwise_fma(pp[kp][2], D2, tv);
            tv = __builtin_elementwise_fma(pp[kp][3], D3, tv);
            tm2 = __builtin_elementwise_max(tm2, tv);
        }
        float t = fmaxf(tm2.x, tm2.y);
        wclog[cc] = t;
        cqm = fmaxf(cqm, t);
    }
    {
        const int kpA[4] = {0, 2, 5, 7};
        #pragma unroll
        for (int kp=0; kp<4; ++kp) {
            s.u.wspart[kpA[kp]  ][q][px] = ws2[kp].x;
            s.u.wspart[kpA[kp]+1][q][px] = ws2[kp].y;
        }
        s.u.wspart[4][q][px] = wsp4;
    }
    s.wcpart[q][px] = cqm;
    __syncthreads();                 // bar1

    // ---- mid: parallel wc-softmax; e values stay in registers ----------
    float ev[16];
    {
        float M = fmaxf(fmaxf(s.wcpart[0][px], s.wcpart[1][px]),
                        fmaxf(s.wcpart[2][px], s.wcpart[3][px]));
        float sum = 0.f;
        #pragma unroll
        for (int cc=0; cc<16; ++cc) {
            float e = __expf(wclog[cc] - M);
            ev[cc] = e;
            sum += e;
        }
        s.wcsum[q][px] = sum;
    }
    if (q == 0) {
        // ws softmax (9 taps) -- wave 0 only (bar1->bar2 critical path).
        float v[9]; float mx = -1e30f;
        #pragma unroll
        for (int k=0;k<9;++k) {
            float a = s.u.wspart[k][0][px];
            a = fmaxf(a, s.u.wspart[k][1][px]);
            a = fmaxf(a, s.u.wspart[k][2][px]);
            a = fmaxf(a, s.u.wspart[k][3][px]);
            v[k]=a; mx=fmaxf(mx,a);
        }
        float sum=0.f;
        #pragma unroll
        for (int k=0;k<9;++k) { v[k]=__expf(v[k]-mx); sum+=v[k]; }
        float inv = 1.0f/sum;
        #pragma unroll
        for (int k=0;k<9;++k) s.wsm[k][px] = v[k]*inv*mkr[k];
    }
    __syncthreads();                 // bar2

    const float winv = 1.0f / (s.wcsum[0][px] + s.wcsum[1][px] +
                               s.wcsum[2][px] + s.wcsum[3][px]);
    float m2r[9];
    #pragma unroll
    for (int k=0;k<9;++k) m2r[k] = mkr[k] * winv;   // hoisted out of tap loop

    // ---------------- phase 2: bf16 MFMA GEMM (round-0/4 structure) -------
    const int lane = tid & 63;
    const int wv   = tid >> 6;
    const int mrow = lane & 31;
    const int half = lane >> 5;
    const int co0  = (wv & 1) * 32;
    const int px0  = (wv >> 1) * 32;

    const short8* aswz = (const short8*)wbf;   // [((kk*4+ks)*2+half)*64 + co]

    f32x16 acc;
    #pragma unroll
    for (int i=0;i<16;++i) acc[i]=0.f;

    for (int kk = 0; kk < 9; ++kk) {
        // A-frag loads: coalesced (32 lanes x 16B contiguous per half), L2-hot;
        // issued before V staging so vmcnt overlaps the LDS work.
        short8 af[4];
        #pragma unroll
        for (int ks=0; ks<4; ++ks)
            af[ks] = aswz[(size_t)(((kk*4+ks)*2+half)*64) + co0 + mrow];

        // stage V chunk: V[px][c] = bf16((a_k + m2*e_c) * feat), pair-cvt.
        // No OOB select needed: mkr[kk]=0 for OOB taps -> a_k=0 and m2=0,
        // so the (clamped-address, finite) feat value is multiplied by 0.
        {
            int di = kk/3 - 1, dj = (kk%3) - 1;
            int hh = h + di;
            int ww = w0 + px + dj;
            int hhc = hh<0?0:(hh>HDIM-1?HDIM-1:hh);
            int wwc = ww<0?0:(ww>WDIM-1?WDIM-1:ww);
            const float* xb = x + ((size_t)(b*XC + 3)*HDIM + hhc)*(size_t)WDIM + wwc;
            float a_k = s.wsm[kk][px];
            float m2  = m2r[kk];
            unsigned int packed[8];
            #pragma unroll
            for (int j=0;j<8;++j) {
                unsigned c0 = 16u*q + 2u*j;
                float f0 = xb[(size_t)c0*HW];
                float f1 = xb[(size_t)(c0+1)*HW];
                float w0f = fmaf(m2, ev[2*j],   a_k) * f0;
                float w1f = fmaf(m2, ev[2*j+1], a_k) * f1;
                __hip_bfloat162 h2 = __float22bfloat162_rn(float2{w0f, w1f});
                unsigned int u; __builtin_memcpy(&u, &h2, 4);
                packed[j] = u;
            }
            uint4* vp = (uint4*)&s.u.V[px][16*q];
            vp[0] = uint4{packed[0],packed[1],packed[2],packed[3]};
            vp[1] = uint4{packed[4],packed[5],packed[6],packed[7]};
        }
        __syncthreads();
        #pragma unroll
        for (int ks=0; ks<4; ++ks) {
            short8 bf = *(const short8*)&s.u.V[px0+mrow][ks*16 + half*8];
            acc = __builtin_amdgcn_mfma_f32_32x32x16_bf16(af[ks], bf, acc, 0, 0, 0);
        }
        __syncthreads();
    }

    // ---------------- epilogue: out (pre-BN) + per-channel partials ----------
    const int pxg = w0 + px0 + mrow;
    #pragma unroll
    for (int reg=0; reg<16; ++reg) {
        int row = (reg&3) + 8*(reg>>2) + 4*half;   // C/D layout, 32x32x16
        int co  = co0 + row;
        float v = acc[reg];
        out[((size_t)(b*COUT+co))*HW + (size_t)h*WDIM + pxg] = v;
        float s1 = v, s2 = v*v;
        #pragma unroll
        for (int m=1; m<32; m<<=1) {
            s1 += __shfl_xor(s1, m, 64);
            s2 += __shfl_xor(s2, m, 64);
        }
        if (mrow == 0) {
            psum[(size_t)co*NB2 + bid*2 + (wv>>1)] = s1;
            psq [(size_t)co*NB2 + bid*2 + (wv>>1)] = s2;
        }
    }
}

__global__ __launch_bounds__(256)
void kernelB(const float* __restrict__ psum, const float* __restrict__ psq,
             float* __restrict__ stats)
{
    int co = blockIdx.x;
    int tid = threadIdx.x;
    float s=0.f, sq=0.f;
    for (int j = tid; j < NB2; j += 256) {
        s  += psum[(size_t)co*NB2 + j];
        sq += psq [(size_t)co*NB2 + j];
    }
    #pragma unroll
    for (int m=1; m<64; m<<=1) { s += __shfl_xor(s,m,64); sq += __shfl_xor(sq,m,64); }
    __shared__ float rs[4], rq[4];
    int wv = tid>>6;
    if ((tid&63)==0){ rs[wv]=s; rq[wv]=sq; }
    __syncthreads();
    if (tid==0) {
        float S = rs[0]+rs[1]+rs[2]+rs[3];
        float Q = rq[0]+rq[1]+rq[2]+rq[3];
        float mu = S / (float)NPIX;
        float var = Q/(float)NPIX - mu*mu;
        stats[co]      = mu;
        stats[64+co]   = rsqrtf(var + EPS);
    }
}

__global__ __launch_bounds__(256)
void kernelC(float* __restrict__ out, const float* __restrict__ stats,
             const float* __restrict__ gamma, const float* __restrict__ beta)
{
    size_t idx8 = (size_t)blockIdx.x*256 + threadIdx.x;
    size_t flat = idx8*8;
    int co = (int)((flat >> 17) & 63);
    float mu = stats[co], rstd = stats[64+co];
    float g  = gamma[co]*rstd;
    float bb = fmaf(-mu, g, beta[co]);
    #pragma unroll
    for (int t=0;t<2;++t) {
        float4 v = *(float4*)(out + flat + t*4);
        v.x = fmaxf(fmaf(v.x, g, bb), 0.f);
        v.y = fmaxf(fmaf(v.y, g, bb), 0.f);
        v.z = fmaxf(fmaf(v.z, g, bb), 0.f);
        v.w = fmaxf(fmaf(v.w, g, bb), 0.f);
        *(float4*)(out + flat + t*4) = v;
    }
}

extern "C" void kernel_launch(void* const* d_in, const int* in_sizes, int n_in,
                              void* d_out, int out_size, void* d_ws, size_t ws_size,
                              hipStream_t stream)
{
    const float* x     = (const float*)d_in[0];
    const int*   mask  = (const int*)  d_in[1];
    const float* w_sp  = (const float*)d_in[2];
    const float* b_sp  = (const float*)d_in[3];
    const float* w_ch  = (const float*)d_in[4];
    const float* b_ch  = (const float*)d_in[5];
    const float* w_agg = (const float*)d_in[6];
    const float* gamma = (const float*)d_in[7];
    const float* beta  = (const float*)d_in[8];
    float* out  = (float*)d_out;
    float* psum = (float*)d_ws;
    float* psq  = psum + (size_t)COUT*NB2;
    float* stats= psq  + (size_t)COUT*NB2;
    unsigned short* wbf = (unsigned short*)(stats + 128);   // 16B-aligned

    kernelW<<<18, 256, 0, stream>>>(w_agg, wbf);
    kernelA<<<NBLK, 256, 0, stream>>>(x, mask, w_sp, b_sp, w_ch, b_ch, wbf, out, psum, psq);
    kernelB<<<COUT, 256, 0, stream>>>(psum, psq, stats);
    int grid_c = (NPIX*COUT/8)/256;   // 8192
    kernelC<<<grid_c, 256, 0, stream>>>(out, stats, gamma, beta);
}

// Round 11
// 244.197 us; speedup vs baseline: 1.0026x; 1.0026x over previous
//
#include <hip/hip_runtime.h>
#include <hip/hip_bf16.h>
#include <math.h>
#include <cstddef>

#define HDIM 64
#define WDIM 2048
#define HW   (HDIM*WDIM)      // 131072
#define BATCH 2
#define CIN  64
#define COUT 64
#define XC   (3+CIN)          // 67
#define NPIX (BATCH*HW)       // 262144
#define NBLK (NPIX/64)        // 4096 blocks, 64 pixels each
#define NB2  (NBLK*2)         // 2 partial slots per block (px halves)
#define EPS  1e-5f

typedef short  short8  __attribute__((ext_vector_type(8)));
typedef float  f32x16  __attribute__((ext_vector_type(16)));

__device__ __forceinline__ unsigned short f2bf(float f) {
    unsigned int u = __float_as_uint(f);
    u += 0x7fff + ((u >> 16) & 1);        // round-to-nearest-even
    return (unsigned short)(u >> 16);
}

// LDS 22,784 B.
// V double-buffered: per barrier interval we stage a PAIR of taps (buf 0/1),
// then run 8 MFMAs. Barriers 18 -> 9; 32 feat loads in flight per interval
// (vs 16) so L2-hit latency (~200cyc post-swizzle) amortizes 2x better.
// V rows padded 64->72 ushorts: b128 frag reads conflict-free (measured 0).
// exp(wc-M) values live in REGISTERS (ev[16]) -- the staging thread (q,px)
// is the same thread that computed them.
struct __align__(16) SmemA {
    float wsm[9][64];            // softmax(ws)[k] * mask[k], [k][px]
    float wcpart[4][64];         // per-wave max of wc logits
    float wcsum[4][64];          // per-wave sum exp(logit - M)
    union {
        unsigned short V[2][64][72]; // weighted feat [px][c] bf16, pair bufs
        float wspart[9][4][64];      // phase-1 ws partial max (dead before V)
    } u;
};

// one-time: w_agg fp32 -> bf16, PRE-SWIZZLED into MFMA fragment order:
// wbf[((kk*4+ks)*2+half)*64 + co][8] = w_agg[co][kk*64+ks*16+half*8 .. +8]
__global__ __launch_bounds__(256)
void kernelW(const float* __restrict__ w_agg, unsigned short* __restrict__ wbf)
{
    int t = blockIdx.x*256 + threadIdx.x;    // 4608 threads total
    int co  = t / 72;
    int rem = t % 72;
    int kk  = rem >> 3;
    int ks  = (rem >> 1) & 3;
    int half= rem & 1;
    const float* src = w_agg + (size_t)co*576 + kk*64 + ks*16 + half*8;
    unsigned long long pk0 = 0, pk1 = 0;
    #pragma unroll
    for (int j=0;j<4;++j) pk0 |= (unsigned long long)f2bf(src[j])   << (16*j);
    #pragma unroll
    for (int j=0;j<4;++j) pk1 |= (unsigned long long)f2bf(src[4+j]) << (16*j);
    unsigned long long* dst =
        (unsigned long long*)(wbf + ((size_t)(((kk*4+ks)*2+half)*64 + co))*8);
    dst[0] = pk0; dst[1] = pk1;
}

// NOTE: min-waves clamp MUST stay at 4. Round 3 used (256,6) -> VGPR forced
// to 40 -> acc/p/wclog spilled to scratch -> FETCH 71->770 MB, 2.9x slower.
// NOTE: stats epilogue MUST stay psum/psq stores (distinct addresses).
// Round 6 used atomicAdd into 128 floats -> 1M same-address atomics ->
// kernelA 136 -> 1597 us (atomic serialization, all pipes idle).
// NOTE: channel loop MUST stay scalar (R8 ch-pair pk spilled; R10 tap-pair
// pk was clean but -14% VALUBusy bought 0 time -> latency-bound, reverted).
__global__ __launch_bounds__(256, 4)
void kernelA(const float* __restrict__ x, const int* __restrict__ mask,
             const float* __restrict__ w_sp, const float* __restrict__ b_sp,
             const float* __restrict__ w_ch, const float* __restrict__ b_ch,
             const unsigned short* __restrict__ wbf,
             float* __restrict__ out, float* __restrict__ psum, float* __restrict__ psq)
{
    __shared__ SmemA s;
    const int tid = threadIdx.x;
    // XCD-aware swizzle (T1): 4096 blocks % 8 XCDs == 0 -> bijective.
    // Measured R9: FETCH 74.5 -> 38.6 MB, kernelA -37 us. KEEP.
    const int bid = ((blockIdx.x & 7) << 9) | (blockIdx.x >> 3);
    const int b  = bid >> 11;
    const int r  = bid & 2047;
    const int h  = r >> 5;
    const int w0 = (r & 31) << 6;

    const int px = tid & 63;
    const int q  = tid >> 6;

    // ---------------- phase 1: per-pixel attention logits ----------------
    float p[9][4];
    float mkr[9];
    {
        const int wpix = w0 + px;
        #pragma unroll
        for (int k = 0; k < 9; ++k) {
            int hh = h + k/3 - 1;
            int ww = wpix + k%3 - 1;
            bool in = (hh >= 0) && (hh < HDIM) && (ww >= 0) && (ww < WDIM);
            float p0=0.f, p1=0.f, p2=0.f, mv=0.f;
            if (in) {
                size_t base = ((size_t)(b*XC)*HDIM + hh)*(size_t)WDIM + ww;
                p0 = x[base];
                p1 = x[base + (size_t)HW];
                p2 = x[base + 2*(size_t)HW];
                mv = (float)mask[((size_t)b*HDIM + hh)*(size_t)WDIM + ww];
            }
            p[k][0]=p0; p[k][1]=p1; p[k][2]=p2;
            p[k][3]=sqrtf(p0*p0 + p1*p1 + p2*p2);
            mkr[k]=mv;
        }
        float c0=p[4][0], c1=p[4][1], c2=p[4][2], c3=p[4][3];
        #pragma unroll
        for (int k = 0; k < 9; ++k) {
            p[k][0]-=c0; p[k][1]-=c1; p[k][2]-=c2; p[k][3]-=c3;
        }
    }

    float wsp[9];
    #pragma unroll
    for (int k=0;k<9;++k) wsp[k] = -1e30f;
    float wclog[16];                 // wc logit (max over taps), in registers
    float cqm = -1e30f;              // wave-partial max over 16 channels
    for (int cc = 0; cc < 16; ++cc) {
        int c = q*16 + cc;                       // wave-uniform -> scalar loads
        float a0=w_sp[c*4+0], a1=w_sp[c*4+1], a2=w_sp[c*4+2], a3=w_sp[c*4+3], bs=b_sp[c];
        float d0=w_ch[c*4+0], d1=w_ch[c*4+1], d2=w_ch[c*4+2], d3=w_ch[c*4+3], bc=b_ch[c];
        // tap 4: p[4] == 0 after centering -> sv=bs, tv=bc
        float tmax = bc;
        wsp[4] = fmaxf(wsp[4], bs);
        #pragma unroll
        for (int k=0;k<9;++k) {
            if (k == 4) continue;
            float sv = fmaf(p[k][0],a0, fmaf(p[k][1],a1, fmaf(p[k][2],a2, fmaf(p[k][3],a3, bs))));
            wsp[k] = fmaxf(wsp[k], sv);
            float tv = fmaf(p[k][0],d0, fmaf(p[k][1],d1, fmaf(p[k][2],d2, fmaf(p[k][3],d3, bc))));
            tmax = fmaxf(tmax, tv);
        }
        wclog[cc] = tmax;
        cqm = fmaxf(cqm, tmax);
    }
    #pragma unroll
    for (int k=0;k<9;++k) s.u.wspart[k][q][px] = wsp[k];
    s.wcpart[q][px] = cqm;
    __syncthreads();                 // bar1

    // ---- mid: parallel wc-softmax; e values stay in registers ----------
    float ev[16];
    {
        float M = fmaxf(fmaxf(s.wcpart[0][px], s.wcpart[1][px]),
                        fmaxf(s.wcpart[2][px], s.wcpart[3][px]));
        float sum = 0.f;
        #pragma unroll
        for (int cc=0; cc<16; ++cc) {
            float e = __expf(wclog[cc] - M);
            ev[cc] = e;
            sum += e;
        }
        s.wcsum[q][px] = sum;
    }
    if (q == 0) {
        // ws softmax (9 taps) -- wave 0 only (bar1->bar2 critical path).
        float v[9]; float mx = -1e30f;
        #pragma unroll
        for (int k=0;k<9;++k) {
            float a = s.u.wspart[k][0][px];
            a = fmaxf(a, s.u.wspart[k][1][px]);
            a = fmaxf(a, s.u.wspart[k][2][px]);
            a = fmaxf(a, s.u.wspart[k][3][px]);
            v[k]=a; mx=fmaxf(mx,a);
        }
        float sum=0.f;
        #pragma unroll
        for (int k=0;k<9;++k) { v[k]=__expf(v[k]-mx); sum+=v[k]; }
        float inv = 1.0f/sum;
        #pragma unroll
        for (int k=0;k<9;++k) s.wsm[k][px] = v[k]*inv*mkr[k];
    }
    __syncthreads();                 // bar2: wspart dead -> V region free

    const float winv = 1.0f / (s.wcsum[0][px] + s.wcsum[1][px] +
                               s.wcsum[2][px] + s.wcsum[3][px]);
    float m2r[9];
    #pragma unroll
    for (int k=0;k<9;++k) m2r[k] = mkr[k] * winv;   // hoisted out of tap loop

    // ---------------- phase 2: pair-staged bf16 MFMA GEMM -----------------
    const int lane = tid & 63;
    const int wv   = tid >> 6;
    const int mrow = lane & 31;
    const int half = lane >> 5;
    const int co0  = (wv & 1) * 32;
    const int px0  = (wv >> 1) * 32;

    const short8* aswz = (const short8*)wbf;   // [((kk*4+ks)*2+half)*64 + co]

    f32x16 acc;
    #pragma unroll
    for (int i=0;i<16;++i) acc[i]=0.f;

    // issue this thread's 16 feat loads for tap kk (clamped addr; OOB taps
    // have m2r=wsm=0 so any finite value is zeroed by the weight).
    auto loadTap = [&](int kk, float* f) {
        int di = kk/3 - 1, dj = (kk%3) - 1;
        int hh = h + di;
        int ww = w0 + px + dj;
        int hhc = hh<0?0:(hh>HDIM-1?HDIM-1:hh);
        int wwc = ww<0?0:(ww>WDIM-1?WDIM-1:ww);
        const float* xb = x + ((size_t)(b*XC + 3)*HDIM + hhc)*(size_t)WDIM + wwc;
        #pragma unroll
        for (int j=0;j<16;++j)
            f[j] = xb[(size_t)(16u*q + j)*HW];
    };
    auto packWrite = [&](int kk, const float* f, int buf) {
        float a_k = s.wsm[kk][px];
        float m2  = m2r[kk];
        unsigned int packed[8];
        #pragma unroll
        for (int j=0;j<8;++j) {
            float w0f = fmaf(m2, ev[2*j],   a_k) * f[2*j];
            float w1f = fmaf(m2, ev[2*j+1], a_k) * f[2*j+1];
            __hip_bfloat162 h2 = __float22bfloat162_rn(float2{w0f, w1f});
            unsigned int u; __builtin_memcpy(&u, &h2, 4);
            packed[j] = u;
        }
        uint4* vp = (uint4*)&s.u.V[buf][px][16*q];
        vp[0] = uint4{packed[0],packed[1],packed[2],packed[3]};
        vp[1] = uint4{packed[4],packed[5],packed[6],packed[7]};
    };
    auto mfmaTap = [&](int kk, int buf) {
        short8 af[4];
        #pragma unroll
        for (int ks=0; ks<4; ++ks)
            af[ks] = aswz[(size_t)(((kk*4+ks)*2+half)*64) + co0 + mrow];
        #pragma unroll
        for (int ks=0; ks<4; ++ks) {
            short8 bf = *(const short8*)&s.u.V[buf][px0+mrow][ks*16 + half*8];
            acc = __builtin_amdgcn_mfma_f32_32x32x16_bf16(af[ks], bf, acc, 0, 0, 0);
        }
    };

    #pragma unroll
    for (int kp = 0; kp < 4; ++kp) {
        const int kA = 2*kp, kB = 2*kp + 1;
        float fa[16], fb[16];
        loadTap(kA, fa);             // 32 loads in flight across both taps
        loadTap(kB, fb);
        packWrite(kA, fa, 0);        // waits only fa; fb still in flight
        packWrite(kB, fb, 1);
        __syncthreads();
        mfmaTap(kA, 0);              // af loads inside cluster caps live regs
        mfmaTap(kB, 1);
        __syncthreads();
    }
    {   // tail tap 8
        float fa[16];
        loadTap(8, fa);
        packWrite(8, fa, 0);
        __syncthreads();
        mfmaTap(8, 0);               // no trailing barrier: no LDS use after
    }

    // ---------------- epilogue: out (pre-BN) + per-channel partials ----------
    const int pxg = w0 + px0 + mrow;
    #pragma unroll
    for (int reg=0; reg<16; ++reg) {
        int row = (reg&3) + 8*(reg>>2) + 4*half;   // C/D layout, 32x32x16
        int co  = co0 + row;
        float v = acc[reg];
        out[((size_t)(b*COUT+co))*HW + (size_t)h*WDIM + pxg] = v;
        float s1 = v, s2 = v*v;
        #pragma unroll
        for (int m=1; m<32; m<<=1) {
            s1 += __shfl_xor(s1, m, 64);
            s2 += __shfl_xor(s2, m, 64);
        }
        if (mrow == 0) {
            psum[(size_t)co*NB2 + bid*2 + (wv>>1)] = s1;
            psq [(size_t)co*NB2 + bid*2 + (wv>>1)] = s2;
        }
    }
}

__global__ __launch_bounds__(256)
void kernelB(const float* __restrict__ psum, const float* __restrict__ psq,
             float* __restrict__ stats)
{
    int co = blockIdx.x;
    int tid = threadIdx.x;
    float s=0.f, sq=0.f;
    for (int j = tid; j < NB2; j += 256) {
        s  += psum[(size_t)co*NB2 + j];
        sq += psq [(size_t)co*NB2 + j];
    }
    #pragma unroll
    for (int m=1; m<64; m<<=1) { s += __shfl_xor(s,m,64); sq += __shfl_xor(sq,m,64); }
    __shared__ float rs[4], rq[4];
    int wv = tid>>6;
    if ((tid&63)==0){ rs[wv]=s; rq[wv]=sq; }
    __syncthreads();
    if (tid==0) {
        float S = rs[0]+rs[1]+rs[2]+rs[3];
        float Q = rq[0]+rq[1]+rq[2]+rq[3];
        float mu = S / (float)NPIX;
        float var = Q/(float)NPIX - mu*mu;
        stats[co]      = mu;
        stats[64+co]   = rsqrtf(var + EPS);
    }
}

__global__ __launch_bounds__(256)
void kernelC(float* __restrict__ out, const float* __restrict__ stats,
             const float* __restrict__ gamma, const float* __restrict__ beta)
{
    size_t idx8 = (size_t)blockIdx.x*256 + threadIdx.x;
    size_t flat = idx8*8;
    int co = (int)((flat >> 17) & 63);
    float mu = stats[co], rstd = stats[64+co];
    float g  = gamma[co]*rstd;
    float bb = fmaf(-mu, g, beta[co]);
    #pragma unroll
    for (int t=0;t<2;++t) {
        float4 v = *(float4*)(out + flat + t*4);
        v.x = fmaxf(fmaf(v.x, g, bb), 0.f);
        v.y = fmaxf(fmaf(v.y, g, bb), 0.f);
        v.z = fmaxf(fmaf(v.z, g, bb), 0.f);
        v.w = fmaxf(fmaf(v.w, g, bb), 0.f);
        *(float4*)(out + flat + t*4) = v;
    }
}

extern "C" void kernel_launch(void* const* d_in, const int* in_sizes, int n_in,
                              void* d_out, int out_size, void* d_ws, size_t ws_size,
                              hipStream_t stream)
{
    const float* x     = (const float*)d_in[0];
    const int*   mask  = (const int*)  d_in[1];
    const float* w_sp  = (const float*)d_in[2];
    const float* b_sp  = (const float*)d_in[3];
    const float* w_ch  = (const float*)d_in[4];
    const float* b_ch  = (const float*)d_in[5];
    const float* w_agg = (const float*)d_in[6];
    const float* gamma = (const float*)d_in[7];
    const float* beta  = (const float*)d_in[8];
    float* out  = (float*)d_out;
    float* psum = (float*)d_ws;
    float* psq  = psum + (size_t)COUT*NB2;
    float* stats= psq  + (size_t)COUT*NB2;
    unsigned short* wbf = (unsigned short*)(stats + 128);   // 16B-aligned

    kernelW<<<18, 256, 0, stream>>>(w_agg, wbf);
    kernelA<<<NBLK, 256, 0, stream>>>(x, mask, w_sp, b_sp, w_ch, b_ch, wbf, out, psum, psq);
    kernelB<<<COUT, 256, 0, stream>>>(psum, psq, stats);
    int grid_c = (NPIX*COUT/8)/256;   // 8192
    kernelC<<<grid_c, 256, 0, stream>>>(out, stats, gamma, beta);
}

// Round 12
// 239.760 us; speedup vs baseline: 1.0212x; 1.0185x over previous
//
#include <hip/hip_runtime.h>
#include <hip/hip_bf16.h>
#include <math.h>
#include <cstddef>

#define HDIM 64
#define WDIM 2048
#define HW   (HDIM*WDIM)      // 131072
#define BATCH 2
#define CIN  64
#define COUT 64
#define XC   (3+CIN)          // 67
#define NPIX (BATCH*HW)       // 262144
#define NBLK (NPIX/64)        // 4096 blocks, 64 pixels each
#define NB2  (NBLK*2)         // 2 partial slots per block (px halves)
#define EPS  1e-5f

typedef short  short8  __attribute__((ext_vector_type(8)));
typedef float  f32x16  __attribute__((ext_vector_type(16)));

__device__ __forceinline__ unsigned short f2bf(float f) {
    unsigned int u = __float_as_uint(f);
    u += 0x7fff + ((u >> 16) & 1);        // round-to-nearest-even
    return (unsigned short)(u >> 16);
}

// LDS 13,568 B.
// V rows padded 64->72 ushorts: b128 frag reads start bank 4*mrow%32 ->
// 8 start groups = conflict-free (measured 0 conflicts rounds 0/4/7/9).
// exp(wc-M) values live in REGISTERS (ev[16]) -- the staging thread (q,px)
// is the same thread that computed them.
struct __align__(16) SmemA {
    float wsm[9][64];            // softmax(ws)[k] * mask[k], [k][px]
    float wcpart[4][64];         // per-wave max of wc logits
    float wcsum[4][64];          // per-wave sum exp(logit - M)
    union {
        unsigned short V[64][72];    // weighted feat [px][c] bf16 (per tap)
        float wspart[9][4][64];      // phase-1 ws partial max (dead before V)
    } u;
};

// one-time: w_agg fp32 -> bf16, PRE-SWIZZLED into MFMA fragment order:
// wbf[((kk*4+ks)*2+half)*64 + co][8] = w_agg[co][kk*64+ks*16+half*8 .. +8]
__global__ __launch_bounds__(256)
void kernelW(const float* __restrict__ w_agg, unsigned short* __restrict__ wbf)
{
    int t = blockIdx.x*256 + threadIdx.x;    // 4608 threads total
    int co  = t / 72;
    int rem = t % 72;
    int kk  = rem >> 3;
    int ks  = (rem >> 1) & 3;
    int half= rem & 1;
    const float* src = w_agg + (size_t)co*576 + kk*64 + ks*16 + half*8;
    unsigned long long pk0 = 0, pk1 = 0;
    #pragma unroll
    for (int j=0;j<4;++j) pk0 |= (unsigned long long)f2bf(src[j])   << (16*j);
    #pragma unroll
    for (int j=0;j<4;++j) pk1 |= (unsigned long long)f2bf(src[4+j]) << (16*j);
    unsigned long long* dst =
        (unsigned long long*)(wbf + ((size_t)(((kk*4+ks)*2+half)*64 + co))*8);
    dst[0] = pk0; dst[1] = pk1;
}

// KernelA == round-9 champion, byte-for-byte. Measured: 116 us, VGPR 64,
// FETCH 38.6 MB, 0 bank conflicts. Frozen invariants (each violated once,
// each cost >10%):
//  - __launch_bounds__(256,4): (256,6) forced VGPR=40 -> scratch spill (R3)
//  - scalar channel loop: pk-packed variants spill (R8) or are null (R10)
//  - psum/psq stores, NOT atomics: R6's 1M same-address atomics = 12x slower
//  - per-tap single-buffer staging: pair/double-buffer variants null (R1,R11)
//  - XCD swizzle: FETCH 74.5 -> 38.6 MB, -37 us (R9)
__global__ __launch_bounds__(256, 4)
void kernelA(const float* __restrict__ x, const int* __restrict__ mask,
             const float* __restrict__ w_sp, const float* __restrict__ b_sp,
             const float* __restrict__ w_ch, const float* __restrict__ b_ch,
             const unsigned short* __restrict__ wbf,
             float* __restrict__ out, float* __restrict__ psum, float* __restrict__ psq)
{
    __shared__ SmemA s;
    const int tid = threadIdx.x;
    // XCD-aware swizzle (T1): 4096 blocks % 8 XCDs == 0 -> bijective.
    const int bid = ((blockIdx.x & 7) << 9) | (blockIdx.x >> 3);
    const int b  = bid >> 11;
    const int r  = bid & 2047;
    const int h  = r >> 5;
    const int w0 = (r & 31) << 6;

    const int px = tid & 63;
    const int q  = tid >> 6;

    // ---------------- phase 1: per-pixel attention logits ----------------
    float p[9][4];
    float mkr[9];
    {
        const int wpix = w0 + px;
        #pragma unroll
        for (int k = 0; k < 9; ++k) {
            int hh = h + k/3 - 1;
            int ww = wpix + k%3 - 1;
            bool in = (hh >= 0) && (hh < HDIM) && (ww >= 0) && (ww < WDIM);
            float p0=0.f, p1=0.f, p2=0.f, mv=0.f;
            if (in) {
                size_t base = ((size_t)(b*XC)*HDIM + hh)*(size_t)WDIM + ww;
                p0 = x[base];
                p1 = x[base + (size_t)HW];
                p2 = x[base + 2*(size_t)HW];
                mv = (float)mask[((size_t)b*HDIM + hh)*(size_t)WDIM + ww];
            }
            p[k][0]=p0; p[k][1]=p1; p[k][2]=p2;
            p[k][3]=sqrtf(p0*p0 + p1*p1 + p2*p2);
            mkr[k]=mv;
        }
        float c0=p[4][0], c1=p[4][1], c2=p[4][2], c3=p[4][3];
        #pragma unroll
        for (int k = 0; k < 9; ++k) {
            p[k][0]-=c0; p[k][1]-=c1; p[k][2]-=c2; p[k][3]-=c3;
        }
    }

    float wsp[9];
    #pragma unroll
    for (int k=0;k<9;++k) wsp[k] = -1e30f;
    float wclog[16];                 // wc logit (max over taps), in registers
    float cqm = -1e30f;              // wave-partial max over 16 channels
    for (int cc = 0; cc < 16; ++cc) {
        int c = q*16 + cc;                       // wave-uniform -> scalar loads
        float a0=w_sp[c*4+0], a1=w_sp[c*4+1], a2=w_sp[c*4+2], a3=w_sp[c*4+3], bs=b_sp[c];
        float d0=w_ch[c*4+0], d1=w_ch[c*4+1], d2=w_ch[c*4+2], d3=w_ch[c*4+3], bc=b_ch[c];
        // tap 4: p[4] == 0 after centering -> sv=bs, tv=bc
        float tmax = bc;
        wsp[4] = fmaxf(wsp[4], bs);
        #pragma unroll
        for (int k=0;k<9;++k) {
            if (k == 4) continue;
            float sv = fmaf(p[k][0],a0, fmaf(p[k][1],a1, fmaf(p[k][2],a2, fmaf(p[k][3],a3, bs))));
            wsp[k] = fmaxf(wsp[k], sv);
            float tv = fmaf(p[k][0],d0, fmaf(p[k][1],d1, fmaf(p[k][2],d2, fmaf(p[k][3],d3, bc))));
            tmax = fmaxf(tmax, tv);
        }
        wclog[cc] = tmax;
        cqm = fmaxf(cqm, tmax);
    }
    #pragma unroll
    for (int k=0;k<9;++k) s.u.wspart[k][q][px] = wsp[k];
    s.wcpart[q][px] = cqm;
    __syncthreads();                 // bar1

    // ---- mid: parallel wc-softmax; e values stay in registers ----------
    float ev[16];
    {
        float M = fmaxf(fmaxf(s.wcpart[0][px], s.wcpart[1][px]),
                        fmaxf(s.wcpart[2][px], s.wcpart[3][px]));
        float sum = 0.f;
        #pragma unroll
        for (int cc=0; cc<16; ++cc) {
            float e = __expf(wclog[cc] - M);
            ev[cc] = e;
            sum += e;
        }
        s.wcsum[q][px] = sum;
    }
    if (q == 0) {
        // ws softmax (9 taps) -- wave 0 only (bar1->bar2 critical path).
        float v[9]; float mx = -1e30f;
        #pragma unroll
        for (int k=0;k<9;++k) {
            float a = s.u.wspart[k][0][px];
            a = fmaxf(a, s.u.wspart[k][1][px]);
            a = fmaxf(a, s.u.wspart[k][2][px]);
            a = fmaxf(a, s.u.wspart[k][3][px]);
            v[k]=a; mx=fmaxf(mx,a);
        }
        float sum=0.f;
        #pragma unroll
        for (int k=0;k<9;++k) { v[k]=__expf(v[k]-mx); sum+=v[k]; }
        float inv = 1.0f/sum;
        #pragma unroll
        for (int k=0;k<9;++k) s.wsm[k][px] = v[k]*inv*mkr[k];
    }
    __syncthreads();                 // bar2

    const float winv = 1.0f / (s.wcsum[0][px] + s.wcsum[1][px] +
                               s.wcsum[2][px] + s.wcsum[3][px]);
    float m2r[9];
    #pragma unroll
    for (int k=0;k<9;++k) m2r[k] = mkr[k] * winv;   // hoisted out of tap loop

    // ---------------- phase 2: bf16 MFMA GEMM (round-0/4 structure) -------
    const int lane = tid & 63;
    const int wv   = tid >> 6;
    const int mrow = lane & 31;
    const int half = lane >> 5;
    const int co0  = (wv & 1) * 32;
    const int px0  = (wv >> 1) * 32;

    const short8* aswz = (const short8*)wbf;   // [((kk*4+ks)*2+half)*64 + co]

    f32x16 acc;
    #pragma unroll
    for (int i=0;i<16;++i) acc[i]=0.f;

    for (int kk = 0; kk < 9; ++kk) {
        // A-frag loads: coalesced (32 lanes x 16B contiguous per half), L2-hot;
        // issued before V staging so vmcnt overlaps the LDS work.
        short8 af[4];
        #pragma unroll
        for (int ks=0; ks<4; ++ks)
            af[ks] = aswz[(size_t)(((kk*4+ks)*2+half)*64) + co0 + mrow];

        // stage V chunk: V[px][c] = bf16((a_k + m2*e_c) * feat), pair-cvt.
        // No OOB select needed: mkr[kk]=0 for OOB taps -> a_k=0 and m2=0,
        // so the (clamped-address, finite) feat value is multiplied by 0.
        {
            int di = kk/3 - 1, dj = (kk%3) - 1;
            int hh = h + di;
            int ww = w0 + px + dj;
            int hhc = hh<0?0:(hh>HDIM-1?HDIM-1:hh);
            int wwc = ww<0?0:(ww>WDIM-1?WDIM-1:ww);
            const float* xb = x + ((size_t)(b*XC + 3)*HDIM + hhc)*(size_t)WDIM + wwc;
            float a_k = s.wsm[kk][px];
            float m2  = m2r[kk];
            unsigned int packed[8];
            #pragma unroll
            for (int j=0;j<8;++j) {
                unsigned c0 = 16u*q + 2u*j;
                float f0 = xb[(size_t)c0*HW];
                float f1 = xb[(size_t)(c0+1)*HW];
                float w0f = fmaf(m2, ev[2*j],   a_k) * f0;
                float w1f = fmaf(m2, ev[2*j+1], a_k) * f1;
                __hip_bfloat162 h2 = __float22bfloat162_rn(float2{w0f, w1f});
                unsigned int u; __builtin_memcpy(&u, &h2, 4);
                packed[j] = u;
            }
            uint4* vp = (uint4*)&s.u.V[px][16*q];
            vp[0] = uint4{packed[0],packed[1],packed[2],packed[3]};
            vp[1] = uint4{packed[4],packed[5],packed[6],packed[7]};
        }
        __syncthreads();
        #pragma unroll
        for (int ks=0; ks<4; ++ks) {
            short8 bf = *(const short8*)&s.u.V[px0+mrow][ks*16 + half*8];
            acc = __builtin_amdgcn_mfma_f32_32x32x16_bf16(af[ks], bf, acc, 0, 0, 0);
        }
        __syncthreads();
    }

    // ---------------- epilogue: out (pre-BN) + per-channel partials ----------
    const int pxg = w0 + px0 + mrow;
    #pragma unroll
    for (int reg=0; reg<16; ++reg) {
        int row = (reg&3) + 8*(reg>>2) + 4*half;   // C/D layout, 32x32x16
        int co  = co0 + row;
        float v = acc[reg];
        out[((size_t)(b*COUT+co))*HW + (size_t)h*WDIM + pxg] = v;
        float s1 = v, s2 = v*v;
        #pragma unroll
        for (int m=1; m<32; m<<=1) {
            s1 += __shfl_xor(s1, m, 64);
            s2 += __shfl_xor(s2, m, 64);
        }
        if (mrow == 0) {
            psum[(size_t)co*NB2 + bid*2 + (wv>>1)] = s1;
            psq [(size_t)co*NB2 + bid*2 + (wv>>1)] = s2;
        }
    }
}

__global__ __launch_bounds__(256)
void kernelB(const float* __restrict__ psum, const float* __restrict__ psq,
             float* __restrict__ stats)
{
    int co = blockIdx.x;
    int tid = threadIdx.x;
    // NB2 = 8192 contiguous partials per channel -> float4 loads (4x fewer
    // issues; this kernel runs on only 64 of 256 CUs, issue-bound).
    const float4* ps4 = (const float4*)(psum + (size_t)co*NB2);
    const float4* pq4 = (const float4*)(psq  + (size_t)co*NB2);
    float s=0.f, sq=0.f;
    for (int j = tid; j < NB2/4; j += 256) {
        float4 a = ps4[j];
        float4 c = pq4[j];
        s  += (a.x + a.y) + (a.z + a.w);
        sq += (c.x + c.y) + (c.z + c.w);
    }
    #pragma unroll
    for (int m=1; m<64; m<<=1) { s += __shfl_xor(s,m,64); sq += __shfl_xor(sq,m,64); }
    __shared__ float rs[4], rq[4];
    int wv = tid>>6;
    if ((tid&63)==0){ rs[wv]=s; rq[wv]=sq; }
    __syncthreads();
    if (tid==0) {
        float S = rs[0]+rs[1]+rs[2]+rs[3];
        float Q = rq[0]+rq[1]+rq[2]+rq[3];
        float mu = S / (float)NPIX;
        float var = Q/(float)NPIX - mu*mu;
        stats[co]      = mu;
        stats[64+co]   = rsqrtf(var + EPS);
    }
}

// 16 floats/thread (verified correct in round 6): 4096 blocks, co uniform
// per block (4096 floats/block << 131072 floats per (b,co) plane, aligned).
__global__ __launch_bounds__(256)
void kernelC(float* __restrict__ out, const float* __restrict__ stats,
             const float* __restrict__ gamma, const float* __restrict__ beta)
{
    size_t idx16 = (size_t)blockIdx.x*256 + threadIdx.x;
    size_t flat = idx16*16;
    int co = (int)((flat >> 17) & 63);
    float mu = stats[co], rstd = stats[64+co];
    float g  = gamma[co]*rstd;
    float bb = fmaf(-mu, g, beta[co]);
    #pragma unroll
    for (int t=0;t<4;++t) {
        float4 v = *(float4*)(out + flat + t*4);
        v.x = fmaxf(fmaf(v.x, g, bb), 0.f);
        v.y = fmaxf(fmaf(v.y, g, bb), 0.f);
        v.z = fmaxf(fmaf(v.z, g, bb), 0.f);
        v.w = fmaxf(fmaf(v.w, g, bb), 0.f);
        *(float4*)(out + flat + t*4) = v;
    }
}

extern "C" void kernel_launch(void* const* d_in, const int* in_sizes, int n_in,
                              void* d_out, int out_size, void* d_ws, size_t ws_size,
                              hipStream_t stream)
{
    const float* x     = (const float*)d_in[0];
    const int*   mask  = (const int*)  d_in[1];
    const float* w_sp  = (const float*)d_in[2];
    const float* b_sp  = (const float*)d_in[3];
    const float* w_ch  = (const float*)d_in[4];
    const float* b_ch  = (const float*)d_in[5];
    const float* w_agg = (const float*)d_in[6];
    const float* gamma = (const float*)d_in[7];
    const float* beta  = (const float*)d_in[8];
    float* out  = (float*)d_out;
    float* psum = (float*)d_ws;
    float* psq  = psum + (size_t)COUT*NB2;
    float* stats= psq  + (size_t)COUT*NB2;
    unsigned short* wbf = (unsigned short*)(stats + 128);   // 16B-aligned

    kernelW<<<18, 256, 0, stream>>>(w_agg, wbf);
    kernelA<<<NBLK, 256, 0, stream>>>(x, mask, w_sp, b_sp, w_ch, b_ch, wbf, out, psum, psq);
    kernelB<<<COUT, 256, 0, stream>>>(psum, psq, stats);
    int grid_c = (NPIX*COUT/16)/256;   // 4096
    kernelC<<<grid_c, 256, 0, stream>>>(out, stats, gamma, beta);
}